// Round 24
// baseline (41.306 us; speedup 1.0000x reference)
//
#include <hip/hip_runtime.h>
#include <math.h>

#define IMG 256
#define NFACE 1000
#define NWAVE 4
#define CAP 512                // survivor list capacity (typ. cnt <= ~350)
#define EPSF 1e-8f
#define LOG2E 1.44269504088896f
#define TCUT 16.0f             // drop contributions with u < -TCUT (<= 1.44*2^-16 each)
#define ACC_BREAK 25.0f        // acc lower bound > 25 -> error < 2^-25
#define RSLACK 7.15f           // 3.5*sqrt(2)*LOG2E: |c(px)-c(center)| in-tile bound

// Static device scratch (graph-capture safe; .bss zero at load).
__device__ float g_rp[IMG][32];   // [row][tile_x] 8-px partial sums (all rewritten)
__device__ int g_bc[32];          // per-band arrival counters (self-resetting)

// Broadcast lane s's register to all lanes (uniform s -> v_readlane).
__device__ __forceinline__ float bcast(float x, int s) {
    return __uint_as_float(__builtin_amdgcn_readlane(__float_as_uint(x), s));
}

// ---------------------------------------------------------------------------
// SINGLE fused kernel. R24 = R23's proven cull+walk with the two-kernel
// structure removed CORRECTLY (R22's regression was the per-block GLOBAL
// vertex gathers, not the fusion: VALUBusy 14%, FETCH 717KB/block):
//   Stage 0: 12 KB vertex array -> LDS (coalesced float4); per-thread camera
//            setup; per-round coefficient compute uses LDS gathers + the
//            EXACT k_coeff arithmetic (bit-identical coefficients).
//   Stage 1: exact corner cull + S_tile bound + LDS survivor append
//            (CAP=512; overflow -> immediate readlane walk, R15 machinery).
//   Stage 2: lane-parallel walk, wave = 8 px x 8 faces (R21/R23 verbatim).
//   Stage 3: conflict-free g_rp[row][bx] partials + per-band arrival counter
//            (threadfence release/acquire); 32nd block of each band reduces
//            and writes out[] directly; counter self-resets (R22-verified).
// Removes: k_coeff launch, inter-kernel EOP/L2-visibility barrier, g_soa
// cold-touch, the 8192-contended-atomic tail, the out[] zeroing pass.
// LDS ~39 KB -> 4 blocks/CU -> all 1024 blocks co-resident.
// ---------------------------------------------------------------------------
__global__ __launch_bounds__(256) void k_all(const float* __restrict__ verts,
                                             const int* __restrict__ faces,
                                             const float* __restrict__ q,
                                             const float* __restrict__ t,
                                             const float* __restrict__ K,
                                             const float* __restrict__ image_ref,
                                             float* __restrict__ out) {
    const int tid = threadIdx.x;
    const int wave = tid >> 6;
    const int lane = tid & 63;
    const int bx = blockIdx.x, by = blockIdx.y;
    const int x0 = bx * 8, y0 = by * 8;
    const float tcx = x0 + 4.0f;   // pixel centers span +0.5..+7.5
    const float tcy = y0 + 4.0f;

    __shared__ __align__(16) float s_v[NFACE * 3];   // 12 KB staged vertices
    __shared__ float4 s_cf[CAP * 3];                 // 24 KB survivor list
    __shared__ float s_acc[NWAVE][64];
    __shared__ float s_ov[NWAVE][64];
    __shared__ float s_S[NWAVE];
    __shared__ int s_cnt;
    __shared__ int s_last;

    if (tid == 0) s_cnt = 0;
    // ---- Stage 0a: stage vertices into LDS (750 x float4, coalesced) ----
    for (int j = tid; j < (NFACE * 3) / 4; j += 256)
        reinterpret_cast<float4*>(s_v)[j] =
            reinterpret_cast<const float4*>(verts)[j];

    // ---- per-thread camera setup (identical arithmetic to old k_coeff) ----
    float qw = q[0], qx = q[1], qy = q[2], qz = q[3];
    float qn = sqrtf(qw * qw + qx * qx + qy * qy + qz * qz + EPSF);
    qw /= qn; qx /= qn; qy /= qn; qz /= qn;
    const float R00 = 1.f - 2.f * (qy * qy + qz * qz);
    const float R01 = 2.f * (qx * qy - qw * qz);
    const float R02 = 2.f * (qx * qz + qw * qy);
    const float R10 = 2.f * (qx * qy + qw * qz);
    const float R11 = 1.f - 2.f * (qx * qx + qz * qz);
    const float R12 = 2.f * (qy * qz - qw * qx);
    const float R20 = 2.f * (qx * qz - qw * qy);
    const float R21 = 2.f * (qy * qz + qw * qx);
    const float R22 = 1.f - 2.f * (qx * qx + qy * qy);
    const float tx = t[0], ty = t[1], tz = t[2];
    const float K00 = K[0], K02 = K[2], K11 = K[4], K12 = K[5];
    __syncthreads();   // s_v staged, s_cnt zeroed

    // ---- Stage 1: per-round coeff compute + cull + S_tile + append ----
    const int wbase = wave * 256;
    const float pxl = x0 + (lane & 7) + 0.5f;   // pixel layout (overflow walk)
    const float pyl = y0 + (lane >> 3) + 0.5f;
    float slb = 0.f;
    float acc_ov = 0.f;
    for (int r = 0; r < 4; ++r) {
        const int f = wbase + r * 64 + lane;
        float c0, c1, c2, c3, c4, c5, c6, c7, c8;
        if (f < NFACE) {
            float X[3], Y[3];
#pragma unroll
            for (int k = 0; k < 3; ++k) {
                int vi = faces[f * 3 + k];
                float vx = s_v[vi * 3 + 0];
                float vy = s_v[vi * 3 + 1];
                float vz = s_v[vi * 3 + 2];
                float cx = R00 * vx + R01 * vy + R02 * vz + tx;
                float cy = R10 * vx + R11 * vy + R12 * vz + ty;
                float cz = R20 * vx + R21 * vy + R22 * vz + tz;
                float z = cz + EPSF;
                X[k] = K00 * cx / z + K02;
                Y[k] = K11 * cy / z + K12;
            }
            float e01x = X[1] - X[0], e01y = Y[1] - Y[0];
            float e02x = X[2] - X[0], e02y = Y[2] - Y[0];
            float area2 = e01x * e02y - e01y * e02x;
            float s = (area2 >= 0.f) ? LOG2E : -LOG2E;
            float ex0 = X[1] - X[0], ey0 = Y[1] - Y[0];
            float inv0 = s / sqrtf(ex0 * ex0 + ey0 * ey0 + EPSF);
            c0 = -ey0 * inv0; c1 = ex0 * inv0;
            c2 = (ey0 * X[0] - ex0 * Y[0]) * inv0;
            float ex1 = X[2] - X[1], ey1 = Y[2] - Y[1];
            float inv1 = s / sqrtf(ex1 * ex1 + ey1 * ey1 + EPSF);
            c3 = -ey1 * inv1; c4 = ex1 * inv1;
            c5 = (ey1 * X[1] - ex1 * Y[1]) * inv1;
            float ex2 = X[0] - X[2], ey2 = Y[0] - Y[2];
            float inv2 = s / sqrtf(ex2 * ex2 + ey2 * ey2 + EPSF);
            c6 = -ey2 * inv2; c7 = ex2 * inv2;
            c8 = (ey2 * X[2] - ex2 * Y[2]) * inv2;
        } else {
            c0 = 0.f; c1 = 0.f; c2 = -1e9f;
            c3 = 0.f; c4 = 0.f; c5 = -1e9f;
            c6 = 0.f; c7 = 0.f; c8 = -1e9f;
        }

        float v0 = fmaf(tcx, c0, fmaf(tcy, c1, c2));
        float v1 = fmaf(tcx, c3, fmaf(tcy, c4, c5));
        float v2 = fmaf(tcx, c6, fmaf(tcy, c7, c8));
        float mc = fminf(fminf(v0, v1), v2);
        slb += fmaxf(mc - RSLACK, 0.f);
        float e0 = v0 + 3.5f * (fabsf(c0) + fabsf(c1));
        float e1 = v1 + 3.5f * (fabsf(c3) + fabsf(c4));
        float e2 = v2 + 3.5f * (fabsf(c6) + fabsf(c7));
        bool hit = (fminf(fminf(e0, e1), e2) > -TCUT);  // exact max-over-tile
        unsigned long long msk = __ballot(hit);
        int n = __popcll(msk);
        int base = 0;
        if (lane == 0) base = atomicAdd(&s_cnt, n);
        base = __builtin_amdgcn_readfirstlane(base);
        int pos = base + __popcll(msk & ((1ull << lane) - 1ull));
        bool ov = hit && (pos >= CAP);
        if (hit && !ov) {
            s_cf[pos * 3 + 0] = make_float4(c0, c1, c2, 0.f);
            s_cf[pos * 3 + 1] = make_float4(c3, c4, c5, 0.f);
            s_cf[pos * 3 + 2] = make_float4(c6, c7, c8, 0.f);
        }
        // overflow fallback (statistically never): immediate readlane walk
        unsigned long long ovm = __ballot(ov);
        while (ovm) {
            int s = __ffsll((unsigned long long)ovm) - 1;
            ovm &= ovm - 1;
            float a0 = bcast(c0, s), a1 = bcast(c1, s), a2 = bcast(c2, s);
            float b0 = bcast(c3, s), b1 = bcast(c4, s), b2 = bcast(c5, s);
            float d0 = bcast(c6, s), d1 = bcast(c7, s), d2 = bcast(c8, s);
            float u = fminf(fminf(fmaf(pxl, a0, fmaf(pyl, a1, a2)),
                                  fmaf(pxl, b0, fmaf(pyl, b1, b2))),
                            fmaf(pxl, d0, fmaf(pyl, d1, d2)));
            acc_ov += fmaxf(u, 0.f);
            acc_ov += __builtin_amdgcn_logf(1.f + __builtin_amdgcn_exp2f(-fabsf(u)));
        }
    }
#pragma unroll
    for (int o = 1; o < 64; o <<= 1) slb += __shfl_xor(slb, o);
    if (lane == 0) s_S[wave] = slb;
    s_ov[wave][lane] = acc_ov;
    __syncthreads();

    const int cntc = min(s_cnt, CAP);
    const int cntp = (cntc + 31) & ~31;         // multiple of 32 (<= 512)
    if (tid < cntp - cntc) {                    // zero-contribution sentinels
        int ppos = cntc + tid;
        s_cf[ppos * 3 + 0] = make_float4(0.f, 0.f, -1e9f, 0.f);
        s_cf[ppos * 3 + 1] = make_float4(0.f, 0.f, -1e9f, 0.f);
        s_cf[ppos * 3 + 2] = make_float4(0.f, 0.f, -1e9f, 0.f);
    }
    __syncthreads();
    const float S_tile = s_S[0] + s_S[1] + s_S[2] + s_S[3];

    // ---- Stage 2: lane-parallel walk (8 px x 8 faces per wave) ----
    if (S_tile <= ACC_BREAK) {
        const int fs = lane >> 3;      // face slot 0..7
        const int ii = lane & 7;       // tile column 0..7
        const float pxc = x0 + ii + 0.5f;
        float acc[8], p[8];
#pragma unroll
        for (int g = 0; g < 8; ++g) { acc[g] = 0.f; p[g] = 1.f; }

        const int nj = cntp >> 3;      // face groups (multiple of 4)
        for (int j = wave; j < nj; j += 4) {
            const int base = (j * 8 + fs) * 3;
            float4 A = s_cf[base + 0];
            float4 B = s_cf[base + 1];
            float4 C = s_cf[base + 2];
#pragma unroll
            for (int g = 0; g < 8; ++g) {
                float pyc = y0 + g + 0.5f;
                float u = fminf(fminf(fmaf(pxc, A.x, fmaf(pyc, A.y, A.z)),
                                      fmaf(pxc, B.x, fmaf(pyc, B.y, B.z))),
                                fmaf(pxc, C.x, fmaf(pyc, C.y, C.z)));
                acc[g] += fmaxf(u, 0.f);
                float e = __builtin_amdgcn_exp2f(-fabsf(u));
                p[g] = fmaf(p[g], e, p[g]);   // p *= (1 + e), <= 2^32 total
            }
        }
#pragma unroll
        for (int g = 0; g < 8; ++g) {
            float a = acc[g] + __builtin_amdgcn_logf(p[g]);
            a += __shfl_xor(a, 8);
            a += __shfl_xor(a, 16);
            a += __shfl_xor(a, 32);           // reduced over the 8 face-lanes
            if (fs == g) s_acc[wave][g * 8 + ii] = a;   // static index
        }
    }
    __syncthreads();

    // ---- Stage 3: sil, sqdiff, row partials, last-block band reduce ----
    if (wave == 0) {
        const int col = x0 + (lane & 7);
        const int row = y0 + (lane >> 3);
        float tot;
        if (S_tile > ACC_BREAK) {
            tot = 32.f;                        // sil == 1.0f exactly
        } else {
            tot = s_acc[0][lane] + s_acc[1][lane] +
                  s_acc[2][lane] + s_acc[3][lane] +
                  s_ov[0][lane] + s_ov[1][lane] +
                  s_ov[2][lane] + s_ov[3][lane];
        }
        float sil = 1.f - __builtin_amdgcn_exp2f(-tot);
        float d = sil - image_ref[row * IMG + col];
        float v = d * d;
        v += __shfl_xor(v, 1);   // sum over the 8 cols of this tile row
        v += __shfl_xor(v, 2);
        v += __shfl_xor(v, 4);
        if ((lane & 7) == 0) g_rp[row][bx] = v;   // conflict-free write
        __threadfence();                           // release
        if (lane == 0) {
            int old = atomicAdd(&g_bc[by], 1);     // device-scope
            s_last = (old == 31);
        }
    }
    __syncthreads();

    if (s_last) {
        __threadfence();                           // acquire
        float v = g_rp[y0 + (tid >> 5)][tid & 31] * (1.f / 256.f);
#pragma unroll
        for (int o = 1; o < 32; o <<= 1) v += __shfl_xor(v, o);
        if ((tid & 31) == 0) out[y0 + (tid >> 5)] = v;
        if (tid == 0) g_bc[by] = 0;                // self-reset for replays
    }
}

// ---------------------------------------------------------------------------
extern "C" void kernel_launch(void* const* d_in, const int* in_sizes, int n_in,
                              void* d_out, int out_size, void* d_ws, size_t ws_size,
                              hipStream_t stream) {
    const float* verts = (const float*)d_in[0];      // (1,1000,3) f32
    const int* faces = (const int*)d_in[1];          // (1,1000,3) i32
    const float* q = (const float*)d_in[2];          // (4,) f32
    const float* t = (const float*)d_in[3];          // (3,) f32
    const float* K = (const float*)d_in[4];          // (3,3) f32
    const float* image_ref = (const float*)d_in[5];  // (256,256) f32
    float* out = (float*)d_out;                      // (256,) f32

    k_all<<<dim3(32, 32), 256, 0, stream>>>(verts, faces, q, t, K, image_ref, out);
}

// Round 26
// 37.071 us; speedup vs baseline: 1.1142x; 1.1142x over previous
//
#include <hip/hip_runtime.h>
#include <math.h>

#define IMG 256
#define NFACE 1000
#define NFP 1024               // padded face count
#define NWAVE 4
#define EPSF 1e-8f
#define LOG2E 1.44269504088896f
#define TCUT 16.0f             // drop contributions with u < -TCUT (<= 1.44*2^-16 each)
#define ACC_BREAK 25.0f        // acc lower bound > 25 -> error < 2^-25
#define RSLACK 7.15f           // 3.5*sqrt(2)*LOG2E: |c(px)-c(center)| in-tile bound

// Static device scratch (graph-capture safe).
// g_soa: SoA (coalesced cull loads). g_cf: AoS 3 x float4 (walk loads).
// Faces >= NFACE self-reject (c2 = -1e9) and contribute exactly 0 in the
// walk (exp2(-1e9) == 0, max(u,0) == 0).
__device__ float g_soa[9][NFP];
__device__ float4 g_cf[NFP * 3];

// ---------------------------------------------------------------------------
// Kernel 1: per-face edge line coefficients (log2e-scaled), SoA + AoS.
// Also zeroes out[] (block 0). Degenerate faces (repeated vertex -> zero
// edge -> c==0 everywhere) need no special case under the line cull.
// ---------------------------------------------------------------------------
__global__ __launch_bounds__(256) void k_coeff(const float* __restrict__ verts,
                                               const int* __restrict__ faces,
                                               const float* __restrict__ q,
                                               const float* __restrict__ t,
                                               const float* __restrict__ K,
                                               float* __restrict__ out) {
    int f = blockIdx.x * 256 + threadIdx.x;   // grid = 4 blocks -> f in [0,1024)
    if (blockIdx.x == 0 && threadIdx.x < IMG) out[threadIdx.x] = 0.f;
    if (f >= NFP) return;

    float c[9];
    if (f < NFACE) {
        float qw = q[0], qx = q[1], qy = q[2], qz = q[3];
        float qn = sqrtf(qw * qw + qx * qx + qy * qy + qz * qz + EPSF);
        qw /= qn; qx /= qn; qy /= qn; qz /= qn;
        float R00 = 1.f - 2.f * (qy * qy + qz * qz);
        float R01 = 2.f * (qx * qy - qw * qz);
        float R02 = 2.f * (qx * qz + qw * qy);
        float R10 = 2.f * (qx * qy + qw * qz);
        float R11 = 1.f - 2.f * (qx * qx + qz * qz);
        float R12 = 2.f * (qy * qz - qw * qx);
        float R20 = 2.f * (qx * qz - qw * qy);
        float R21 = 2.f * (qy * qz + qw * qx);
        float R22 = 1.f - 2.f * (qx * qx + qy * qy);
        float tx = t[0], ty = t[1], tz = t[2];
        float K00 = K[0], K02 = K[2], K11 = K[4], K12 = K[5];

        float X[3], Y[3];
#pragma unroll
        for (int k = 0; k < 3; ++k) {
            int vi = faces[f * 3 + k];
            float vx = verts[vi * 3 + 0];
            float vy = verts[vi * 3 + 1];
            float vz = verts[vi * 3 + 2];
            float cx = R00 * vx + R01 * vy + R02 * vz + tx;
            float cy = R10 * vx + R11 * vy + R12 * vz + ty;
            float cz = R20 * vx + R21 * vy + R22 * vz + tz;
            float z = cz + EPSF;
            X[k] = K00 * cx / z + K02;
            Y[k] = K11 * cy / z + K12;
        }

        float e01x = X[1] - X[0], e01y = Y[1] - Y[0];
        float e02x = X[2] - X[0], e02y = Y[2] - Y[0];
        float area2 = e01x * e02y - e01y * e02x;
        float s = (area2 >= 0.f) ? LOG2E : -LOG2E;

#pragma unroll
        for (int k = 0; k < 3; ++k) {
            int k1 = (k + 1) % 3;
            float ex = X[k1] - X[k];
            float ey = Y[k1] - Y[k];
            float inv = s / sqrtf(ex * ex + ey * ey + EPSF);
            c[k * 3 + 0] = -ey * inv;
            c[k * 3 + 1] = ex * inv;
            c[k * 3 + 2] = (ey * X[k] - ex * Y[k]) * inv;
        }
    } else {
        c[0] = 0.f; c[1] = 0.f; c[2] = -1e9f;
        c[3] = 0.f; c[4] = 0.f; c[5] = -1e9f;
        c[6] = 0.f; c[7] = 0.f; c[8] = -1e9f;
    }

#pragma unroll
    for (int k = 0; k < 9; ++k) g_soa[k][f] = c[k];
    g_cf[f * 3 + 0] = make_float4(c[0], c[1], c[2], 0.f);
    g_cf[f * 3 + 1] = make_float4(c[3], c[4], c[5], 0.f);
    g_cf[f * 3 + 2] = make_float4(c[6], c[7], c[8], 0.f);
}

// ---------------------------------------------------------------------------
// Kernel 2: UNIFORM issue-bound render+loss. R26 = R25 with the divergent-
// ballot bug fixed: __any(anyhit) must execute at FULL CONVERGENCE (inside
// `if (lane==0)` it only saw lane 0's predicate -> band tiles misclassified
// as exterior, absmax 0.119). Everything else unchanged:
//  Phase A: classification only - S_tile lower bound (interior: sil == 1.0)
//    and block-OR corner test (exterior: sil == 0). No lists, no atomics.
//  Phase B: band tiles (~30%) run the lane-parallel all-pairs walk, wave =
//    8 px x 8 faces over all 1024 padded faces from L2-hot g_cf. Branch-free.
// LDS = 1.3 KB. Block = 8x8 tile, 4 waves.
// ---------------------------------------------------------------------------
__global__ __launch_bounds__(256) void k_main(const float* __restrict__ image_ref,
                                              float* __restrict__ out) {
    const int tid = threadIdx.x;
    const int wave = tid >> 6;
    const int lane = tid & 63;
    const int x0 = blockIdx.x * 8, y0 = blockIdx.y * 8;
    const float tcx = x0 + 4.0f;   // pixel centers span +0.5..+7.5
    const float tcy = y0 + 4.0f;

    __shared__ float s_acc[NWAVE][64];
    __shared__ float s_S[NWAVE];
    __shared__ int s_any[NWAVE];

    // ---- Phase A: classification (no survivor list) ----
    const int wbase = wave * 256;
    float slb = 0.f;
    bool anyhit = false;
#pragma unroll
    for (int r = 0; r < 4; ++r) {
        const int f = wbase + r * 64 + lane;
        float l0 = g_soa[0][f], l1 = g_soa[1][f], l2 = g_soa[2][f];
        float l3 = g_soa[3][f], l4 = g_soa[4][f], l5 = g_soa[5][f];
        float l6 = g_soa[6][f], l7 = g_soa[7][f], l8 = g_soa[8][f];
        float c0 = fmaf(tcx, l0, fmaf(tcy, l1, l2));
        float c1 = fmaf(tcx, l3, fmaf(tcy, l4, l5));
        float c2 = fmaf(tcx, l6, fmaf(tcy, l7, l8));
        float mc = fminf(fminf(c0, c1), c2);
        slb += fmaxf(mc - RSLACK, 0.f);
        float e0 = c0 + 3.5f * (fabsf(l0) + fabsf(l1));
        float e1 = c1 + 3.5f * (fabsf(l3) + fabsf(l4));
        float e2 = c2 + 3.5f * (fabsf(l6) + fabsf(l7));
        anyhit = anyhit || (fminf(fminf(e0, e1), e2) > -TCUT);
    }
#pragma unroll
    for (int o = 1; o < 64; o <<= 1) slb += __shfl_xor(slb, o);
    const int anyw = __any(anyhit) ? 1 : 0;   // ballot at FULL convergence
    if (lane == 0) {
        s_S[wave] = slb;
        s_any[wave] = anyw;
    }
    __syncthreads();
    const float S_tile = s_S[0] + s_S[1] + s_S[2] + s_S[3];
    const int band = (s_any[0] | s_any[1] | s_any[2] | s_any[3]);

    // ---- Phase B: all-pairs lane-parallel walk (band tiles only) ----
    if (S_tile <= ACC_BREAK && band) {
        const int fs = lane >> 3;      // face slot 0..7
        const int ii = lane & 7;       // tile column 0..7
        const float pxc = x0 + ii + 0.5f;
        float acc[8], p[8];
#pragma unroll
        for (int g = 0; g < 8; ++g) { acc[g] = 0.f; p[g] = 1.f; }

        for (int j = wave; j < NFP / 8; j += 4) {   // 32 iterations
            const int base = (j * 8 + fs) * 3;
            float4 A = g_cf[base + 0];
            float4 B = g_cf[base + 1];
            float4 C = g_cf[base + 2];
#pragma unroll
            for (int g = 0; g < 8; ++g) {
                float pyc = y0 + g + 0.5f;
                float u = fminf(fminf(fmaf(pxc, A.x, fmaf(pyc, A.y, A.z)),
                                      fmaf(pxc, B.x, fmaf(pyc, B.y, B.z))),
                                fmaf(pxc, C.x, fmaf(pyc, C.y, C.z)));
                acc[g] += fmaxf(u, 0.f);
                float e = __builtin_amdgcn_exp2f(-fabsf(u));
                p[g] = fmaf(p[g], e, p[g]);   // p *= (1 + e), <= 2^32 total
            }
        }
#pragma unroll
        for (int g = 0; g < 8; ++g) {
            float a = acc[g] + __builtin_amdgcn_logf(p[g]);
            a += __shfl_xor(a, 8);
            a += __shfl_xor(a, 16);
            a += __shfl_xor(a, 32);           // reduced over the 8 face-lanes
            if (fs == g) s_acc[wave][g * 8 + ii] = a;   // static index
        }
    }
    __syncthreads();

    // ---- combine, sil, sqdiff, row-reduce, atomic row partial ----
    if (wave == 0) {
        const int col = x0 + (lane & 7);
        const int row = y0 + (lane >> 3);
        float tot;
        if (S_tile > ACC_BREAK) tot = 32.f;        // sil == 1.0f exactly
        else if (!band) tot = 0.f;                 // sil ~= 0 (exterior)
        else tot = s_acc[0][lane] + s_acc[1][lane] +
                   s_acc[2][lane] + s_acc[3][lane];
        float sil = 1.f - __builtin_amdgcn_exp2f(-tot);
        float d = sil - image_ref[row * IMG + col];
        float v = d * d;
        v += __shfl_xor(v, 1);   // sum over the 8 cols of this tile row
        v += __shfl_xor(v, 2);
        v += __shfl_xor(v, 4);
        if ((lane & 7) == 0) atomicAdd(&out[row], v * (1.f / 256.f));
    }
}

// ---------------------------------------------------------------------------
extern "C" void kernel_launch(void* const* d_in, const int* in_sizes, int n_in,
                              void* d_out, int out_size, void* d_ws, size_t ws_size,
                              hipStream_t stream) {
    const float* verts = (const float*)d_in[0];      // (1,1000,3) f32
    const int* faces = (const int*)d_in[1];          // (1,1000,3) i32
    const float* q = (const float*)d_in[2];          // (4,) f32
    const float* t = (const float*)d_in[3];          // (3,) f32
    const float* K = (const float*)d_in[4];          // (3,3) f32
    const float* image_ref = (const float*)d_in[5];  // (256,256) f32
    float* out = (float*)d_out;                      // (256,) f32

    k_coeff<<<NFP / 256, 256, 0, stream>>>(verts, faces, q, t, K, out);
    k_main<<<dim3(IMG / 8, IMG / 8), 256, 0, stream>>>(image_ref, out);
}

// Round 27
// 20.393 us; speedup vs baseline: 2.0255x; 1.8178x over previous
//
#include <hip/hip_runtime.h>
#include <math.h>

#define IMG 256
#define NFACE 1000
#define NFP 1024               // padded face count; 4 waves x 256 faces (4 rounds)
#define NWAVE 4
#define CAP 1024               // survivor list capacity: cnt <= 1000, cntp <= 1024
#define EPSF 1e-8f
#define LOG2E 1.44269504088896f
#define TCUT 16.0f             // drop contributions with u < -TCUT (<= 1.44*2^-16 each)
#define ACC_BREAK 25.0f        // acc lower bound > 25 -> error < 2^-25
#define RSLACK 7.15f           // 3.5*sqrt(2)*LOG2E: |c(px)-c(center)| in-tile bound

// Static device scratch (graph-capture safe). SoA: 9 arrays of 1024 floats.
// Faces >= NFACE are self-rejecting pads (c2 = -1e9 -> never survive cull).
__device__ float g_soa[9][NFP];

// ---------------------------------------------------------------------------
// Kernel 1: per-face edge line coefficients (log2e-scaled), SoA.
// Also zeroes out[] (block 0). Degenerate faces (repeated vertex -> zero
// edge -> c==0 everywhere, face paints an infinite line band) need no
// special case under the line-distance cull.
// ---------------------------------------------------------------------------
__global__ __launch_bounds__(256) void k_coeff(const float* __restrict__ verts,
                                               const int* __restrict__ faces,
                                               const float* __restrict__ q,
                                               const float* __restrict__ t,
                                               const float* __restrict__ K,
                                               float* __restrict__ out) {
    int f = blockIdx.x * 256 + threadIdx.x;   // grid = 4 blocks -> f in [0,1024)
    if (blockIdx.x == 0 && threadIdx.x < IMG) out[threadIdx.x] = 0.f;
    if (f >= NFP) return;

    float c[9];
    if (f < NFACE) {
        float qw = q[0], qx = q[1], qy = q[2], qz = q[3];
        float qn = sqrtf(qw * qw + qx * qx + qy * qy + qz * qz + EPSF);
        qw /= qn; qx /= qn; qy /= qn; qz /= qn;
        float R00 = 1.f - 2.f * (qy * qy + qz * qz);
        float R01 = 2.f * (qx * qy - qw * qz);
        float R02 = 2.f * (qx * qz + qw * qy);
        float R10 = 2.f * (qx * qy + qw * qz);
        float R11 = 1.f - 2.f * (qx * qx + qz * qz);
        float R12 = 2.f * (qy * qz - qw * qx);
        float R20 = 2.f * (qx * qz - qw * qy);
        float R21 = 2.f * (qy * qz + qw * qx);
        float R22 = 1.f - 2.f * (qx * qx + qy * qy);
        float tx = t[0], ty = t[1], tz = t[2];
        float K00 = K[0], K02 = K[2], K11 = K[4], K12 = K[5];

        float X[3], Y[3];
#pragma unroll
        for (int k = 0; k < 3; ++k) {
            int vi = faces[f * 3 + k];
            float vx = verts[vi * 3 + 0];
            float vy = verts[vi * 3 + 1];
            float vz = verts[vi * 3 + 2];
            float cx = R00 * vx + R01 * vy + R02 * vz + tx;
            float cy = R10 * vx + R11 * vy + R12 * vz + ty;
            float cz = R20 * vx + R21 * vy + R22 * vz + tz;
            float z = cz + EPSF;
            X[k] = K00 * cx / z + K02;
            Y[k] = K11 * cy / z + K12;
        }

        float e01x = X[1] - X[0], e01y = Y[1] - Y[0];
        float e02x = X[2] - X[0], e02y = Y[2] - Y[0];
        float area2 = e01x * e02y - e01y * e02x;
        float s = (area2 >= 0.f) ? LOG2E : -LOG2E;

#pragma unroll
        for (int k = 0; k < 3; ++k) {
            int k1 = (k + 1) % 3;
            float ex = X[k1] - X[k];
            float ey = Y[k1] - Y[k];
            float inv = s / sqrtf(ex * ex + ey * ey + EPSF);
            c[k * 3 + 0] = -ey * inv;
            c[k * 3 + 1] = ex * inv;
            c[k * 3 + 2] = (ey * X[k] - ex * Y[k]) * inv;
        }
    } else {
        c[0] = 0.f; c[1] = 0.f; c[2] = -1e9f;
        c[3] = 0.f; c[4] = 0.f; c[5] = -1e9f;
        c[6] = 0.f; c[7] = 0.f; c[8] = -1e9f;
    }

#pragma unroll
    for (int k = 0; k < 9; ++k) g_soa[k][f] = c[k];
}

// ---------------------------------------------------------------------------
// Kernel 2: fused render+loss (best-known configuration, R23 = 20.59 us):
// exact corner cull + S_tile interior skip + LDS survivor compaction +
// lane-parallel walk (wave = 8 px x 8 faces) + product-trick softplus,
// bit-reversed block -> tile mapping.
// ---------------------------------------------------------------------------
__global__ __launch_bounds__(256) void k_main(const float* __restrict__ image_ref,
                                              float* __restrict__ out) {
    const int tid = threadIdx.x;
    const int wave = tid >> 6;
    const int lane = tid & 63;
    const int bid = blockIdx.x;                    // 0..1023
    const int tile = (int)(__brev((unsigned)bid) >> 22);   // 10-bit reversal
    const int x0 = (tile & 31) * 8, y0 = (tile >> 5) * 8;
    const float tcx = x0 + 4.0f;   // pixel centers span +0.5..+7.5
    const float tcy = y0 + 4.0f;

    __shared__ float4 s_cf[CAP * 3];    // 48 KB survivor coeff list
    __shared__ float s_acc[NWAVE][64];
    __shared__ float s_S[NWAVE];
    __shared__ int s_cnt;

    if (tid == 0) s_cnt = 0;
    __syncthreads();

    // ---- Phase A: cull (exact corner test) + S_tile bound + append ----
    const int wbase = wave * 256;
    float slb = 0.f;
    for (int r = 0; r < 4; ++r) {
        const int f = wbase + r * 64 + lane;
        float l0 = g_soa[0][f], l1 = g_soa[1][f], l2 = g_soa[2][f];
        float l3 = g_soa[3][f], l4 = g_soa[4][f], l5 = g_soa[5][f];
        float l6 = g_soa[6][f], l7 = g_soa[7][f], l8 = g_soa[8][f];
        float c0 = fmaf(tcx, l0, fmaf(tcy, l1, l2));
        float c1 = fmaf(tcx, l3, fmaf(tcy, l4, l5));
        float c2 = fmaf(tcx, l6, fmaf(tcy, l7, l8));
        float mc = fminf(fminf(c0, c1), c2);
        slb += fmaxf(mc - RSLACK, 0.f);
        float e0 = c0 + 3.5f * (fabsf(l0) + fabsf(l1));
        float e1 = c1 + 3.5f * (fabsf(l3) + fabsf(l4));
        float e2 = c2 + 3.5f * (fabsf(l6) + fabsf(l7));
        bool hit = (fminf(fminf(e0, e1), e2) > -TCUT);  // exact max-over-tile
        unsigned long long msk = __ballot(hit);
        int n = __popcll(msk);
        int base = 0;
        if (lane == 0) base = atomicAdd(&s_cnt, n);
        base = __builtin_amdgcn_readfirstlane(base);
        int pos = base + __popcll(msk & ((1ull << lane) - 1ull));
        if (hit) {
            s_cf[pos * 3 + 0] = make_float4(l0, l1, l2, 0.f);
            s_cf[pos * 3 + 1] = make_float4(l3, l4, l5, 0.f);
            s_cf[pos * 3 + 2] = make_float4(l6, l7, l8, 0.f);
        }
    }
#pragma unroll
    for (int o = 1; o < 64; o <<= 1) slb += __shfl_xor(slb, o);
    if (lane == 0) s_S[wave] = slb;
    __syncthreads();

    const int cnt = s_cnt;
    const int cntp = (cnt + 31) & ~31;          // multiple of 32 (<= 1024)
    if (tid < cntp - cnt) {                     // zero-contribution sentinels
        int ppos = cnt + tid;
        s_cf[ppos * 3 + 0] = make_float4(0.f, 0.f, -1e9f, 0.f);
        s_cf[ppos * 3 + 1] = make_float4(0.f, 0.f, -1e9f, 0.f);
        s_cf[ppos * 3 + 2] = make_float4(0.f, 0.f, -1e9f, 0.f);
    }
    __syncthreads();
    const float S_tile = s_S[0] + s_S[1] + s_S[2] + s_S[3];

    // ---- Phase B: lane-parallel walk (8 px x 8 faces per wave) ----
    if (S_tile <= ACC_BREAK) {
        const int fs = lane >> 3;      // face slot 0..7
        const int ii = lane & 7;       // tile column 0..7
        const float pxc = x0 + ii + 0.5f;
        float acc[8], p[8];
#pragma unroll
        for (int g = 0; g < 8; ++g) { acc[g] = 0.f; p[g] = 1.f; }

        const int nj = cntp >> 3;      // face groups (multiple of 4)
        for (int j = wave; j < nj; j += 4) {
            const int base = (j * 8 + fs) * 3;
            float4 A = s_cf[base + 0];
            float4 B = s_cf[base + 1];
            float4 C = s_cf[base + 2];
#pragma unroll
            for (int g = 0; g < 8; ++g) {
                float pyc = y0 + g + 0.5f;
                float u = fminf(fminf(fmaf(pxc, A.x, fmaf(pyc, A.y, A.z)),
                                      fmaf(pxc, B.x, fmaf(pyc, B.y, B.z))),
                                fmaf(pxc, C.x, fmaf(pyc, C.y, C.z)));
                acc[g] += fmaxf(u, 0.f);
                float e = __builtin_amdgcn_exp2f(-fabsf(u));
                p[g] = fmaf(p[g], e, p[g]);   // p *= (1 + e), <= 2^32 total
            }
        }
#pragma unroll
        for (int g = 0; g < 8; ++g) {
            float a = acc[g] + __builtin_amdgcn_logf(p[g]);
            a += __shfl_xor(a, 8);
            a += __shfl_xor(a, 16);
            a += __shfl_xor(a, 32);           // reduced over the 8 face-lanes
            if (fs == g) s_acc[wave][g * 8 + ii] = a;   // static index
        }
    }
    __syncthreads();

    // ---- combine waves, sil, sqdiff, row-reduce, atomic row partial ----
    if (wave == 0) {
        const int col = x0 + (lane & 7);
        const int row = y0 + (lane >> 3);
        float tot = (S_tile > ACC_BREAK)
                        ? 32.f                 // sil == 1.0f exactly
                        : (s_acc[0][lane] + s_acc[1][lane] +
                           s_acc[2][lane] + s_acc[3][lane]);
        float sil = 1.f - __builtin_amdgcn_exp2f(-tot);
        float d = sil - image_ref[row * IMG + col];
        float v = d * d;
        v += __shfl_xor(v, 1);   // sum over the 8 cols of this tile row
        v += __shfl_xor(v, 2);
        v += __shfl_xor(v, 4);
        if ((lane & 7) == 0) atomicAdd(&out[row], v * (1.f / 256.f));
    }
}

// ---------------------------------------------------------------------------
extern "C" void kernel_launch(void* const* d_in, const int* in_sizes, int n_in,
                              void* d_out, int out_size, void* d_ws, size_t ws_size,
                              hipStream_t stream) {
    const float* verts = (const float*)d_in[0];      // (1,1000,3) f32
    const int* faces = (const int*)d_in[1];          // (1,1000,3) i32
    const float* q = (const float*)d_in[2];          // (4,) f32
    const float* t = (const float*)d_in[3];          // (3,) f32
    const float* K = (const float*)d_in[4];          // (3,3) f32
    const float* image_ref = (const float*)d_in[5];  // (256,256) f32
    float* out = (float*)d_out;                      // (256,) f32

    k_coeff<<<NFP / 256, 256, 0, stream>>>(verts, faces, q, t, K, out);
    k_main<<<1024, 256, 0, stream>>>(image_ref, out);
}